// Round 13
// baseline (281.881 us; speedup 1.0000x reference)
//
#include <hip/hip_runtime.h>
#include <hip/hip_bf16.h>

#define IN_F   1024
#define OUT_F  1024
#define TOKENS 8192
#define KTOT   9216
#define KHALF  4608
#define NTILE  72          // KHALF / 64
#define NBA    ((TOKENS * IN_F) / 256)        // prep_fused A blocks
#define NBB    ((OUT_F * (KTOT / 8)) / 256)   // prep_fused B blocks

typedef __attribute__((ext_vector_type(8))) short  bf16x8;
typedef __attribute__((ext_vector_type(8))) unsigned short ushortx8;
typedef __attribute__((ext_vector_type(4))) float  f32x4;

template<int M> struct ModeT { static constexpr int value = M; };

__device__ __forceinline__ unsigned int f2bf(float f) {
    union { float f; unsigned int u; } v; v.f = f;
    unsigned int r = v.u + 0x7fffu + ((v.u >> 16) & 1u);
    return r >> 16;
}

__device__ __forceinline__ float bf2f(unsigned short h) {
    union { unsigned int u; float f; } v; v.u = ((unsigned int)h) << 16;
    return v.f;
}

__device__ __forceinline__ void prep_a_body(int idx, const float* __restrict__ x,
                                            const float* __restrict__ grid,
                                            unsigned short* __restrict__ A)
{
    int t = idx >> 10;
    int i = idx & 1023;
    float xv = x[idx];
    float sil = xv / (1.0f + __expf(-xv));
    A[(size_t)t * KTOT + i] = (unsigned short)f2bf(sil);

    const float invd = 1.0f / (2.0f / 7.0f + 1e-5f);
    unsigned int h[8];
    #pragma unroll
    for (int g = 0; g < 8; ++g) {
        float d = (xv - grid[g]) * invd;
        h[g] = f2bf(__expf(-d * d));
    }
    uint4 pk;
    pk.x = h[0] | (h[1] << 16);
    pk.y = h[2] | (h[3] << 16);
    pk.z = h[4] | (h[5] << 16);
    pk.w = h[6] | (h[7] << 16);
    *reinterpret_cast<uint4*>(&A[(size_t)t * KTOT + IN_F + (size_t)i * 8]) = pk;
}

__device__ __forceinline__ void prep_b_body(int idx, const float* __restrict__ W,
                                            const float* __restrict__ spl,
                                            unsigned short* __restrict__ B)
{
    int o  = idx / (KTOT / 8);
    int c8 = idx - o * (KTOT / 8);
    const float* src = (c8 < IN_F / 8)
        ? (W   + (size_t)o * IN_F     + (size_t)c8 * 8)
        : (spl + (size_t)o * IN_F * 8 + (size_t)(c8 - IN_F / 8) * 8);
    const float4* s4 = reinterpret_cast<const float4*>(src);
    float4 lo = s4[0], hi = s4[1];
    uint4 pk;
    pk.x = f2bf(lo.x) | (f2bf(lo.y) << 16);
    pk.y = f2bf(lo.z) | (f2bf(lo.w) << 16);
    pk.z = f2bf(hi.x) | (f2bf(hi.y) << 16);
    pk.w = f2bf(hi.z) | (f2bf(hi.w) << 16);
    *reinterpret_cast<uint4*>(&B[(size_t)o * KTOT + (size_t)c8 * 8]) = pk;
}

// Fused A+B prep; one extra trailing block zeroes the split-K counters.
__global__ __launch_bounds__(256)
void prep_fused(const float* __restrict__ x, const float* __restrict__ grid,
                const float* __restrict__ W, const float* __restrict__ spl,
                unsigned short* __restrict__ A, unsigned short* __restrict__ B,
                int* __restrict__ cnt)
{
    int b = blockIdx.x;
    if (b >= NBA + NBB) {
        if (threadIdx.x < 128) cnt[threadIdx.x] = 0;
        return;
    }
    if (b < NBA)
        prep_a_body(b * 256 + threadIdx.x, x, grid, A);
    else
        prep_b_body((b - NBA) * 256 + threadIdx.x, W, spl, B);
}

__global__ __launch_bounds__(256)
void prep_a_kernel(const float* __restrict__ x, const float* __restrict__ grid,
                   unsigned short* __restrict__ A)
{
    prep_a_body(blockIdx.x * blockDim.x + threadIdx.x, x, grid, A);
}

__global__ __launch_bounds__(256)
void prep_b_kernel(const float* __restrict__ W, const float* __restrict__ spl,
                   unsigned short* __restrict__ B)
{
    prep_b_body(blockIdx.x * blockDim.x + threadIdx.x, W, spl, B);
}

// ---------------------------------------------------------------------------
// 256x256 tile, BK=64, 8 waves (2M x 4N), split-K=2.
// R6/R11/R12 barrier-minimal body (proven: gemm 126 us, MfmaUtil 54%,
// 0 conflicts) + A-locality XCD remap (FETCH halved) + BF16 partials.
// R13: FUSED split-K reduction (rocBLAS/CK last-writer pattern): both sk
// blocks write bf16 partials; threadfence + atomicAdd per (bm,bn) tile;
// second arriver re-reads peer partial, adds own acc (f32, in regs) + bias,
// writes f32 out. Removes the serial reduce kernel; finish traffic overlaps
// in-flight MFMA of other blocks. Agent-scope fences handle XCD L2
// non-coherence (G16).
//   A row(mi) = wr*64 + (mi&3)*16 + (mi>>2)*128
//   B col(ni) = wc*32 + (ni&1)*16 + (ni>>1)*128
// ---------------------------------------------------------------------------
#define GLOAD(src, dst) __builtin_amdgcn_global_load_lds( \
    (const __attribute__((address_space(1))) void*)(src),  \
    (__attribute__((address_space(3))) void*)(dst), 16, 0, 0)
#define SBAR()  __builtin_amdgcn_s_barrier()
#define SCH0()  __builtin_amdgcn_sched_barrier(0)
#define VMC0()  asm volatile("s_waitcnt vmcnt(0)" ::: "memory")

__global__ __launch_bounds__(512, 2)
void gemm_kan2(const unsigned short* __restrict__ A,
               const unsigned short* __restrict__ B,
               unsigned short* __restrict__ P, int rows,
               float* __restrict__ out, const float* __restrict__ bias,
               int* __restrict__ cnt, int fuse)
{
    __shared__ char lds[131072];   // A dbuf [0,64K), B dbuf [64K,128K)

    const int bid  = blockIdx.x;
    // A-locality remap (R8/R12-proven): xcd = bid&7 (round-robin dispatch);
    // bm == xcd (mod 8) -> the 8 (bn,sk) siblings of one bm share one XCD's L2.
    const int xcd  = bid & 7;
    const int j    = bid >> 3;
    const int sk   = j & 1;
    const int bn   = (j >> 1) & 3;
    const int bm   = (j >> 3) * 8 + xcd;
    const int tid  = threadIdx.x;
    const int wave = tid >> 6, lane = tid & 63;
    const int wr   = wave >> 2, wc = wave & 3;
    const int fr   = lane & 15, kg = lane >> 4;
    const int sw   = fr & 7;
    const int koff[2] = { (kg ^ sw) * 16, ((4 | kg) ^ sw) * 16 };
    const int k0 = sk * KHALF;

    // staging: thread covers row (tid>>3), 16B chunk (tid&7), inverse-swizzled k
    const int trow = tid >> 3;
    const int ksrc = ((tid & 7) ^ (trow & 7)) * 8;
    const unsigned short* gA = A + (size_t)(bm * 256 + trow) * KTOT + k0 + ksrc;
    const unsigned short* gB = B + (size_t)(bn * 256 + trow) * KTOT + k0 + ksrc;
    const size_t R64 = (size_t)64 * KTOT;

    f32x4 acc[8][4];
    const f32x4 zero = {0.f, 0.f, 0.f, 0.f};
    #pragma unroll
    for (int m = 0; m < 8; ++m)
        #pragma unroll
        for (int n = 0; n < 4; ++n) acc[m][n] = zero;

    // prologue: stage tile 0 -> buf0
    {
        char* dA = lds + tid * 16;
        char* dB = lds + 65536 + tid * 16;
        GLOAD(gA,           dA);           GLOAD(gA + R64,     dA + 8192);
        GLOAD(gA + 2 * R64, dA + 16384);   GLOAD(gA + 3 * R64, dA + 24576);
        GLOAD(gB,           dB);           GLOAD(gB + R64,     dB + 8192);
        GLOAD(gB + 2 * R64, dB + 16384);   GLOAD(gB + 3 * R64, dB + 24576);
        gA += 64; gB += 64;
    }
    VMC0(); SBAR(); SCH0();

    const int aOff = (wr * 64 + fr) * 128;   // + (mi&3)*2048; +16384 for hi half
    const int bOff = (wc * 32 + fr) * 128;   // + (ni&1)*2048; +16384 for hi half

    bf16x8 af[4][2], bfLo[2][2], bfHi[2][2];
    int u = 0;

    // MODE: 0 = steady (stages tile u+1), 1 = last tile (no staging)
    auto tile = [&](auto mC) {
        constexpr int MODE = decltype(mC)::value;
        char* bufA = lds + (u & 1) * 32768;
        char* bufB = lds + 65536 + (u & 1) * 32768;

        // ---- reads: af-lo, bfLo, bfHi (16 x ds_read_b128) ----
        #pragma unroll
        for (int mi = 0; mi < 4; ++mi)
            #pragma unroll
            for (int ks = 0; ks < 2; ++ks)
                af[mi][ks] = *(const bf16x8*)(bufA + aOff + mi * 2048 + koff[ks]);
        #pragma unroll
        for (int ni = 0; ni < 2; ++ni)
            #pragma unroll
            for (int ks = 0; ks < 2; ++ks) {
                bfLo[ni][ks] = *(const bf16x8*)(bufB + bOff + ni * 2048 + koff[ks]);
                bfHi[ni][ks] = *(const bf16x8*)(bufB + bOff + 16384 + ni * 2048 + koff[ks]);
            }

        // ---- stage tile u+1 into the other buffers ----
        if constexpr (MODE == 0) {
            char* dA = lds + ((u & 1) ^ 1) * 32768 + tid * 16;
            char* dB = lds + 65536 + ((u & 1) ^ 1) * 32768 + tid * 16;
            GLOAD(gA,           dA);           GLOAD(gA + R64,     dA + 8192);
            GLOAD(gA + 2 * R64, dA + 16384);   GLOAD(gA + 3 * R64, dA + 24576);
            GLOAD(gB,           dB);           GLOAD(gB + R64,     dB + 8192);
            GLOAD(gB + 2 * R64, dB + 16384);   GLOAD(gB + 3 * R64, dB + 24576);
            gA += 64; gB += 64;
        }
        SCH0();

        // ---- q00: af-lo x bfLo ----
        __builtin_amdgcn_s_setprio(1);
        #pragma unroll
        for (int mi = 0; mi < 4; ++mi)
            #pragma unroll
            for (int ni = 0; ni < 2; ++ni)
                #pragma unroll
                for (int ks = 0; ks < 2; ++ks)
                    acc[mi][ni] = __builtin_amdgcn_mfma_f32_16x16x32_bf16(
                        af[mi][ks], bfLo[ni][ks], acc[mi][ni], 0, 0, 0);
        __builtin_amdgcn_s_setprio(0);

        // ---- q01: af-lo x bfHi ----
        __builtin_amdgcn_s_setprio(1);
        #pragma unroll
        for (int mi = 0; mi < 4; ++mi)
            #pragma unroll
            for (int ni = 0; ni < 2; ++ni)
                #pragma unroll
                for (int ks = 0; ks < 2; ++ks)
                    acc[mi][2 + ni] = __builtin_amdgcn_mfma_f32_16x16x32_bf16(
                        af[mi][ks], bfHi[ni][ks], acc[mi][2 + ni], 0, 0, 0);
        __builtin_amdgcn_s_setprio(0);

        // ---- af-hi reads (8 x ds_read_b128), overlap q01 drain ----
        #pragma unroll
        for (int mi = 0; mi < 4; ++mi)
            #pragma unroll
            for (int ks = 0; ks < 2; ++ks)
                af[mi][ks] = *(const bf16x8*)(bufA + aOff + 16384 + mi * 2048 + koff[ks]);

        // ---- q10: af-hi x bfLo ----
        __builtin_amdgcn_s_setprio(1);
        #pragma unroll
        for (int mi = 0; mi < 4; ++mi)
            #pragma unroll
            for (int ni = 0; ni < 2; ++ni)
                #pragma unroll
                for (int ks = 0; ks < 2; ++ks)
                    acc[4 + mi][ni] = __builtin_amdgcn_mfma_f32_16x16x32_bf16(
                        af[mi][ks], bfLo[ni][ks], acc[4 + mi][ni], 0, 0, 0);
        __builtin_amdgcn_s_setprio(0);

        // ---- q11: af-hi x bfHi ----
        __builtin_amdgcn_s_setprio(1);
        #pragma unroll
        for (int mi = 0; mi < 4; ++mi)
            #pragma unroll
            for (int ni = 0; ni < 2; ++ni)
                #pragma unroll
                for (int ks = 0; ks < 2; ++ks)
                    acc[4 + mi][2 + ni] = __builtin_amdgcn_mfma_f32_16x16x32_bf16(
                        af[mi][ks], bfHi[ni][ks], acc[4 + mi][2 + ni], 0, 0, 0);
        __builtin_amdgcn_s_setprio(0);

        SCH0();
        if constexpr (MODE == 0) {
            VMC0();          // tile u+1 resident (issued a full tile ago)
            SBAR(); SCH0();  // all waves done reading buf(u); safe to overwrite next
        }
    };

    for (u = 0; u < NTILE - 1; ++u) tile(ModeT<0>{});
    tile(ModeT<1>{});

    // epilogue: write own BF16 partial (interleaved-quadrant mapping)
    unsigned short* Pown = P + (size_t)sk * rows * OUT_F;
    const size_t orow0 = (size_t)bm * 256 + (size_t)wr * 64;
    const int    ocol0 = bn * 256 + wc * 32;
    #pragma unroll
    for (int n = 0; n < 4; ++n) {
        const int col = ocol0 + (n & 1) * 16 + (n >> 1) * 128 + fr;
        #pragma unroll
        for (int m = 0; m < 8; ++m) {
            const size_t r0 = orow0 + (m & 3) * 16 + (m >> 2) * 128 + kg * 4;
            #pragma unroll
            for (int j2 = 0; j2 < 4; ++j2)
                Pown[(r0 + j2) * OUT_F + col] = (unsigned short)f2bf(acc[m][n][j2]);
        }
    }
    if (!fuse) return;

    // fused split-K finish: last arriver folds peer partial + bias -> out
    __threadfence();                 // release: partial visible device-wide
    __syncthreads();                 // whole block's stores fenced
    __shared__ int role;
    if (tid == 0) role = atomicAdd(&cnt[(bm << 2) | bn], 1);
    __syncthreads();
    if (role == 0) return;           // first arriver: peer will finish
    __threadfence();                 // acquire: invalidate before peer reads

    const unsigned short* Poth = P + (size_t)(sk ^ 1) * rows * OUT_F;
    #pragma unroll
    for (int n = 0; n < 4; ++n) {
        const int col = ocol0 + (n & 1) * 16 + (n >> 1) * 128 + fr;
        const float bv = bias[col];
        #pragma unroll
        for (int m = 0; m < 8; ++m) {
            const size_t r0 = orow0 + (m & 3) * 16 + (m >> 2) * 128 + kg * 4;
            #pragma unroll
            for (int j2 = 0; j2 < 4; ++j2) {
                const size_t off = (r0 + j2) * OUT_F + col;
                out[off] = acc[m][n][j2] + bf2f(Poth[off]) + bv;
            }
        }
    }
}

// out = P0 + P1 + bias   (fallback path only)
__global__ __launch_bounds__(256)
void reduce_kan(const unsigned short* __restrict__ P,
                const float* __restrict__ bias,
                float* __restrict__ out, int n8, int skStride8)
{
    const ushortx8* p0 = (const ushortx8*)P;
    const ushortx8* p1 = p0 + skStride8;
    const float4* bv = (const float4*)bias;
    float4* o = (float4*)out;
    for (int i = blockIdx.x * blockDim.x + threadIdx.x; i < n8;
         i += gridDim.x * blockDim.x) {
        ushortx8 a = p0[i], b = p1[i];
        float4 c0 = bv[(i & 127) * 2], c1 = bv[(i & 127) * 2 + 1];
        float4 r0, r1;
        r0.x = bf2f(a[0]) + bf2f(b[0]) + c0.x;
        r0.y = bf2f(a[1]) + bf2f(b[1]) + c0.y;
        r0.z = bf2f(a[2]) + bf2f(b[2]) + c0.z;
        r0.w = bf2f(a[3]) + bf2f(b[3]) + c0.w;
        r1.x = bf2f(a[4]) + bf2f(b[4]) + c1.x;
        r1.y = bf2f(a[5]) + bf2f(b[5]) + c1.y;
        r1.z = bf2f(a[6]) + bf2f(b[6]) + c1.z;
        r1.w = bf2f(a[7]) + bf2f(b[7]) + c1.w;
        o[i * 2]     = r0;
        o[i * 2 + 1] = r1;
    }
}

extern "C" void kernel_launch(void* const* d_in, const int* in_sizes, int n_in,
                              void* d_out, int out_size, void* d_ws, size_t ws_size,
                              hipStream_t stream)
{
    const float* x    = (const float*)d_in[0];
    const float* W    = (const float*)d_in[1];
    const float* bias = (const float*)d_in[2];
    const float* spl  = (const float*)d_in[3];
    const float* grid = (const float*)d_in[4];
    float* out = (float*)d_out;

    unsigned short* Bw = (unsigned short*)d_ws;               // 18.9 MB
    unsigned short* Aw = Bw + (size_t)OUT_F * KTOT;

    // per-row ws: A bf16 (18432 B) + 2x bf16 partial (4096 B); +1KB counters
    const size_t bBytes = (size_t)OUT_F * KTOT * 2;
    size_t avail = ws_size > bBytes + 1024 ? ws_size - bBytes - 1024 : 0;
    long maxRows = (long)(avail / 22528);
    int chunk = (maxRows >= TOKENS) ? TOKENS : (int)((maxRows / 256) * 256);
    if (chunk < 256) chunk = 256;
    unsigned short* Pp = Aw + (size_t)chunk * KTOT;
    int* cnt = (int*)(Pp + (size_t)2 * chunk * OUT_F);

    if (chunk == TOKENS) {
        // fused prep (A + B + counter-zero), GEMM with fused split-K finish
        prep_fused<<<NBA + NBB + 1, 256, 0, stream>>>(x, grid, W, spl, Aw, Bw, cnt);
        gemm_kan2<<<(TOKENS >> 8) * 8, 512, 0, stream>>>(
            Aw, Bw, Pp, TOKENS, out, bias, cnt, 1);
    } else {
        prep_b_kernel<<<NBB, 256, 0, stream>>>(W, spl, Bw);
        for (int t0 = 0; t0 < TOKENS; t0 += chunk) {
            int rows = (TOKENS - t0 < chunk) ? (TOKENS - t0) : chunk;
            prep_a_kernel<<<(rows * IN_F) / 256, 256, 0, stream>>>(
                x + (size_t)t0 * IN_F, grid, Aw);
            gemm_kan2<<<(rows >> 8) * 8, 512, 0, stream>>>(
                Aw, Bw, Pp, rows, out + (size_t)t0 * OUT_F, bias, cnt, 0);
            int n8 = rows * 128;
            int rblocks = (n8 + 255) / 256; if (rblocks > 2048) rblocks = 2048;
            reduce_kan<<<rblocks, 256, 0, stream>>>(
                Pp, bias, out + (size_t)t0 * OUT_F, n8, n8);
        }
    }
}

// Round 14
// 194.795 us; speedup vs baseline: 1.4471x; 1.4471x over previous
//
#include <hip/hip_runtime.h>
#include <hip/hip_bf16.h>

#define IN_F   1024
#define OUT_F  1024
#define TOKENS 8192
#define KTOT   9216
#define KHALF  4608
#define NTILE  72          // KHALF / 64
#define NBA    ((TOKENS * IN_F) / 256)        // prep_fused A blocks
#define NBB    ((OUT_F * (KTOT / 8)) / 256)   // prep_fused B blocks

typedef __attribute__((ext_vector_type(8))) short  bf16x8;
typedef __attribute__((ext_vector_type(8))) unsigned short ushortx8;
typedef __attribute__((ext_vector_type(4))) float  f32x4;

template<int M> struct ModeT { static constexpr int value = M; };

__device__ __forceinline__ unsigned int f2bf(float f) {
    union { float f; unsigned int u; } v; v.f = f;
    unsigned int r = v.u + 0x7fffu + ((v.u >> 16) & 1u);
    return r >> 16;
}

__device__ __forceinline__ float bf2f(unsigned short h) {
    union { unsigned int u; float f; } v; v.u = ((unsigned int)h) << 16;
    return v.f;
}

__device__ __forceinline__ void prep_a_body(int idx, const float* __restrict__ x,
                                            const float* __restrict__ grid,
                                            unsigned short* __restrict__ A)
{
    int t = idx >> 10;
    int i = idx & 1023;
    float xv = x[idx];
    float sil = xv / (1.0f + __expf(-xv));
    A[(size_t)t * KTOT + i] = (unsigned short)f2bf(sil);

    const float invd = 1.0f / (2.0f / 7.0f + 1e-5f);
    unsigned int h[8];
    #pragma unroll
    for (int g = 0; g < 8; ++g) {
        float d = (xv - grid[g]) * invd;
        h[g] = f2bf(__expf(-d * d));
    }
    uint4 pk;
    pk.x = h[0] | (h[1] << 16);
    pk.y = h[2] | (h[3] << 16);
    pk.z = h[4] | (h[5] << 16);
    pk.w = h[6] | (h[7] << 16);
    *reinterpret_cast<uint4*>(&A[(size_t)t * KTOT + IN_F + (size_t)i * 8]) = pk;
}

__device__ __forceinline__ void prep_b_body(int idx, const float* __restrict__ W,
                                            const float* __restrict__ spl,
                                            unsigned short* __restrict__ B)
{
    int o  = idx / (KTOT / 8);
    int c8 = idx - o * (KTOT / 8);
    const float* src = (c8 < IN_F / 8)
        ? (W   + (size_t)o * IN_F     + (size_t)c8 * 8)
        : (spl + (size_t)o * IN_F * 8 + (size_t)(c8 - IN_F / 8) * 8);
    const float4* s4 = reinterpret_cast<const float4*>(src);
    float4 lo = s4[0], hi = s4[1];
    uint4 pk;
    pk.x = f2bf(lo.x) | (f2bf(lo.y) << 16);
    pk.y = f2bf(lo.z) | (f2bf(lo.w) << 16);
    pk.z = f2bf(hi.x) | (f2bf(hi.y) << 16);
    pk.w = f2bf(hi.z) | (f2bf(hi.w) << 16);
    *reinterpret_cast<uint4*>(&B[(size_t)o * KTOT + (size_t)c8 * 8]) = pk;
}

// Fused A+B prep: blocks [0, NBA) build A (silu + basis), rest repack B.
__global__ __launch_bounds__(256)
void prep_fused(const float* __restrict__ x, const float* __restrict__ grid,
                const float* __restrict__ W, const float* __restrict__ spl,
                unsigned short* __restrict__ A, unsigned short* __restrict__ B)
{
    int b = blockIdx.x;
    if (b < NBA)
        prep_a_body(b * 256 + threadIdx.x, x, grid, A);
    else
        prep_b_body((b - NBA) * 256 + threadIdx.x, W, spl, B);
}

__global__ __launch_bounds__(256)
void prep_a_kernel(const float* __restrict__ x, const float* __restrict__ grid,
                   unsigned short* __restrict__ A)
{
    prep_a_body(blockIdx.x * blockDim.x + threadIdx.x, x, grid, A);
}

__global__ __launch_bounds__(256)
void prep_b_kernel(const float* __restrict__ W, const float* __restrict__ spl,
                   unsigned short* __restrict__ B)
{
    prep_b_body(blockIdx.x * blockDim.x + threadIdx.x, W, spl, B);
}

// ---------------------------------------------------------------------------
// R14: 128x128 tile, BK=64, 4 waves (2M x 2N, per-wave 64x64), split-K=2.
// Rationale: operand redundancy 2 on BOTH A and B (vs 4 on A at 256²) drops
// LDS traffic to 0.046 B/MAC (was 0.062); LDS/block = 64 KB -> 2 blocks/CU
// co-resident with INDEPENDENT barrier domains (first inter-block overlap).
// Dispatch makes the co-resident pair share (bn,sk): same B panel in L2.
// Proven pieces kept: barrier-minimal body (1 barrier + 1 vmcnt(0)/tile),
// XOR swizzle (row stride 128 B unchanged), bf16 partials, separate reduce,
// A-locality XCD remap (bm == xcd mod 8).
//   A row(mi) = wr*64 + mi*16 ; B col(ni) = wc*64 + ni*16
// ---------------------------------------------------------------------------
#define GLOAD(src, dst) __builtin_amdgcn_global_load_lds( \
    (const __attribute__((address_space(1))) void*)(src),  \
    (__attribute__((address_space(3))) void*)(dst), 16, 0, 0)
#define SBAR()  __builtin_amdgcn_s_barrier()
#define SCH0()  __builtin_amdgcn_sched_barrier(0)
#define VMC0()  asm volatile("s_waitcnt vmcnt(0)" ::: "memory")

__global__ __launch_bounds__(256, 2)
void gemm_kan2(const unsigned short* __restrict__ A,
               const unsigned short* __restrict__ B,
               unsigned short* __restrict__ P, int rows)
{
    __shared__ char lds[65536];   // A: buf0 [0,16K) buf1 [16K,32K); B: +32K

    const int bid  = blockIdx.x;
    // xcd = bid&7 (round-robin dispatch); bm == xcd (mod 8) -> the 16 (bn,sk)
    // siblings of one bm share one XCD's L2 A-slice. Co-resident pair on a CU
    // (bid, bid+256) shares (bn,sk) -> same B panel in L2.
    const int xcd  = bid & 7;
    const int j    = bid >> 3;
    const int sk   = j & 1;
    const int bn   = (j >> 1) & 7;
    const int bm   = (j >> 4) * 8 + xcd;
    const int tid  = threadIdx.x;
    const int wave = tid >> 6, lane = tid & 63;
    const int wr   = wave >> 1, wc = wave & 1;
    const int fr   = lane & 15, kg = lane >> 4;
    const int sw   = fr & 7;
    const int koff[2] = { (kg ^ sw) * 16, ((4 | kg) ^ sw) * 16 };
    const int k0 = sk * KHALF;

    // staging: thread covers row (tid>>3) (+32 per r), chunk (tid&7),
    // inverse-swizzled k. 4 A + 4 B gloads per thread per tile.
    const int trow = tid >> 3;
    const int ksrc = ((tid & 7) ^ (trow & 7)) * 8;
    const unsigned short* gA = A + (size_t)(bm * 128 + trow) * KTOT + k0 + ksrc;
    const unsigned short* gB = B + (size_t)(bn * 128 + trow) * KTOT + k0 + ksrc;
    const size_t R32 = (size_t)32 * KTOT;

    f32x4 acc[4][4];
    const f32x4 zero = {0.f, 0.f, 0.f, 0.f};
    #pragma unroll
    for (int m = 0; m < 4; ++m)
        #pragma unroll
        for (int n = 0; n < 4; ++n) acc[m][n] = zero;

    // prologue: stage tile 0 -> buf0
    {
        char* dA = lds + tid * 16;
        char* dB = lds + 32768 + tid * 16;
        #pragma unroll
        for (int r = 0; r < 4; ++r) {
            GLOAD(gA + r * R32, dA + r * 4096);
            GLOAD(gB + r * R32, dB + r * 4096);
        }
        gA += 64; gB += 64;
    }
    VMC0(); SBAR(); SCH0();

    const int aOff = (wr * 64 + fr) * 128;   // + mi*2048
    const int bOff = (wc * 64 + fr) * 128;   // + ni*2048

    bf16x8 af[4][2], bf[4][2];
    int u = 0;

    // MODE: 0 = steady (stages tile u+1), 1 = last tile (no staging)
    auto tile = [&](auto mC) {
        constexpr int MODE = decltype(mC)::value;
        char* bufA = lds + (u & 1) * 16384;
        char* bufB = lds + 32768 + (u & 1) * 16384;

        // ---- reads: af (8) + bf (8) x ds_read_b128 ----
        #pragma unroll
        for (int mi = 0; mi < 4; ++mi)
            #pragma unroll
            for (int ks = 0; ks < 2; ++ks) {
                af[mi][ks] = *(const bf16x8*)(bufA + aOff + mi * 2048 + koff[ks]);
                bf[mi][ks] = *(const bf16x8*)(bufB + bOff + mi * 2048 + koff[ks]);
            }

        // ---- stage tile u+1 into the other buffers ----
        if constexpr (MODE == 0) {
            char* dA = lds + ((u & 1) ^ 1) * 16384 + tid * 16;
            char* dB = lds + 32768 + ((u & 1) ^ 1) * 16384 + tid * 16;
            #pragma unroll
            for (int r = 0; r < 4; ++r) {
                GLOAD(gA + r * R32, dA + r * 4096);
                GLOAD(gB + r * R32, dB + r * 4096);
            }
            gA += 64; gB += 64;
        }
        SCH0();

        // ---- 32 MFMA ----
        __builtin_amdgcn_s_setprio(1);
        #pragma unroll
        for (int mi = 0; mi < 4; ++mi)
            #pragma unroll
            for (int ni = 0; ni < 4; ++ni)
                #pragma unroll
                for (int ks = 0; ks < 2; ++ks)
                    acc[mi][ni] = __builtin_amdgcn_mfma_f32_16x16x32_bf16(
                        af[mi][ks], bf[ni][ks], acc[mi][ni], 0, 0, 0);
        __builtin_amdgcn_s_setprio(0);

        SCH0();
        if constexpr (MODE == 0) {
            VMC0();          // tile u+1 resident (issued a full tile ago)
            SBAR(); SCH0();  // all waves done reading buf(u)
        }
    };

    for (u = 0; u < NTILE - 1; ++u) tile(ModeT<0>{});
    tile(ModeT<1>{});

    // epilogue: write BF16 partials
    unsigned short* Pp = P + (size_t)sk * rows * OUT_F;
    const size_t orow0 = (size_t)bm * 128 + (size_t)wr * 64;
    const int    ocol0 = bn * 128 + wc * 64;
    #pragma unroll
    for (int n = 0; n < 4; ++n) {
        const int col = ocol0 + n * 16 + fr;
        #pragma unroll
        for (int m = 0; m < 4; ++m) {
            const size_t r0 = orow0 + m * 16 + kg * 4;
            #pragma unroll
            for (int j2 = 0; j2 < 4; ++j2)
                Pp[(r0 + j2) * OUT_F + col] = (unsigned short)f2bf(acc[m][n][j2]);
        }
    }
}

// out = P0 + P1 + bias   (bf16 partials, f32 out; 8 elems/thread)
__global__ __launch_bounds__(256)
void reduce_kan(const unsigned short* __restrict__ P,
                const float* __restrict__ bias,
                float* __restrict__ out, int n8, int skStride8)
{
    const ushortx8* p0 = (const ushortx8*)P;
    const ushortx8* p1 = p0 + skStride8;
    const float4* bv = (const float4*)bias;
    float4* o = (float4*)out;
    for (int i = blockIdx.x * blockDim.x + threadIdx.x; i < n8;
         i += gridDim.x * blockDim.x) {
        ushortx8 a = p0[i], b = p1[i];
        float4 c0 = bv[(i & 127) * 2], c1 = bv[(i & 127) * 2 + 1];
        float4 r0, r1;
        r0.x = bf2f(a[0]) + bf2f(b[0]) + c0.x;
        r0.y = bf2f(a[1]) + bf2f(b[1]) + c0.y;
        r0.z = bf2f(a[2]) + bf2f(b[2]) + c0.z;
        r0.w = bf2f(a[3]) + bf2f(b[3]) + c0.w;
        r1.x = bf2f(a[4]) + bf2f(b[4]) + c1.x;
        r1.y = bf2f(a[5]) + bf2f(b[5]) + c1.y;
        r1.z = bf2f(a[6]) + bf2f(b[6]) + c1.z;
        r1.w = bf2f(a[7]) + bf2f(b[7]) + c1.w;
        o[i * 2]     = r0;
        o[i * 2 + 1] = r1;
    }
}

extern "C" void kernel_launch(void* const* d_in, const int* in_sizes, int n_in,
                              void* d_out, int out_size, void* d_ws, size_t ws_size,
                              hipStream_t stream)
{
    const float* x    = (const float*)d_in[0];
    const float* W    = (const float*)d_in[1];
    const float* bias = (const float*)d_in[2];
    const float* spl  = (const float*)d_in[3];
    const float* grid = (const float*)d_in[4];
    float* out = (float*)d_out;

    unsigned short* Bw = (unsigned short*)d_ws;               // 18.9 MB
    unsigned short* Aw = Bw + (size_t)OUT_F * KTOT;

    // per-row ws: A bf16 (18432 B) + 2x bf16 partial (4096 B) = 22528 B
    const size_t bBytes = (size_t)OUT_F * KTOT * 2;
    size_t avail = ws_size > bBytes ? ws_size - bBytes : 0;
    long maxRows = (long)(avail / 22528);
    // chunk multiple of 1024 (bm-mapping needs row-groups of 8 x 128)
    int chunk = (maxRows >= TOKENS) ? TOKENS : (int)((maxRows / 1024) * 1024);
    if (chunk < 1024) chunk = 1024;
    unsigned short* Pp = Aw + (size_t)chunk * KTOT;

    if (chunk == TOKENS) {
        // fused prep (A + B in one BW-bound sweep), then one GEMM + reduce
        prep_fused<<<NBA + NBB, 256, 0, stream>>>(x, grid, W, spl, Aw, Bw);
        gemm_kan2<<<(TOKENS >> 7) * 16, 256, 0, stream>>>(Aw, Bw, Pp, TOKENS);
        int n8 = TOKENS * 128;
        reduce_kan<<<2048, 256, 0, stream>>>(Pp, bias, out, n8, n8);
    } else {
        prep_b_kernel<<<NBB, 256, 0, stream>>>(W, spl, Bw);
        for (int t0 = 0; t0 < TOKENS; t0 += chunk) {
            int rows = (TOKENS - t0 < chunk) ? (TOKENS - t0) : chunk;
            prep_a_kernel<<<(rows * IN_F) / 256, 256, 0, stream>>>(
                x + (size_t)t0 * IN_F, grid, Aw);
            gemm_kan2<<<(rows >> 7) * 16, 256, 0, stream>>>(Aw, Bw, Pp, rows);
            int n8 = rows * 128;
            int rblocks = (n8 + 255) / 256; if (rblocks > 2048) rblocks = 2048;
            reduce_kan<<<rblocks, 256, 0, stream>>>(
                Pp, bias, out + (size_t)t0 * OUT_F, n8, n8);
        }
    }
}

// Round 15
// 174.631 us; speedup vs baseline: 1.6142x; 1.1155x over previous
//
#include <hip/hip_runtime.h>
#include <hip/hip_bf16.h>

#define IN_F   1024
#define OUT_F  1024
#define TOKENS 8192
#define KTOT   9216
#define KHALF  4608
#define NTILE  72          // KHALF / 64
#define NBA    ((TOKENS * IN_F) / 256)        // prep_fused A blocks
#define NBB    ((OUT_F * (KTOT / 8)) / 256)   // prep_fused B blocks

typedef __attribute__((ext_vector_type(8))) short  bf16x8;
typedef __attribute__((ext_vector_type(8))) unsigned short ushortx8;
typedef __attribute__((ext_vector_type(4))) float  f32x4;

template<int M> struct ModeT { static constexpr int value = M; };

__device__ __forceinline__ unsigned int f2bf(float f) {
    union { float f; unsigned int u; } v; v.f = f;
    unsigned int r = v.u + 0x7fffu + ((v.u >> 16) & 1u);
    return r >> 16;
}

__device__ __forceinline__ float bf2f(unsigned short h) {
    union { unsigned int u; float f; } v; v.u = ((unsigned int)h) << 16;
    return v.f;
}

__device__ __forceinline__ void prep_a_body(int idx, const float* __restrict__ x,
                                            const float* __restrict__ grid,
                                            unsigned short* __restrict__ A)
{
    int t = idx >> 10;
    int i = idx & 1023;
    float xv = x[idx];
    float sil = xv / (1.0f + __expf(-xv));
    A[(size_t)t * KTOT + i] = (unsigned short)f2bf(sil);

    const float invd = 1.0f / (2.0f / 7.0f + 1e-5f);
    unsigned int h[8];
    #pragma unroll
    for (int g = 0; g < 8; ++g) {
        float d = (xv - grid[g]) * invd;
        h[g] = f2bf(__expf(-d * d));
    }
    uint4 pk;
    pk.x = h[0] | (h[1] << 16);
    pk.y = h[2] | (h[3] << 16);
    pk.z = h[4] | (h[5] << 16);
    pk.w = h[6] | (h[7] << 16);
    *reinterpret_cast<uint4*>(&A[(size_t)t * KTOT + IN_F + (size_t)i * 8]) = pk;
}

__device__ __forceinline__ void prep_b_body(int idx, const float* __restrict__ W,
                                            const float* __restrict__ spl,
                                            unsigned short* __restrict__ B)
{
    int o  = idx / (KTOT / 8);
    int c8 = idx - o * (KTOT / 8);
    const float* src = (c8 < IN_F / 8)
        ? (W   + (size_t)o * IN_F     + (size_t)c8 * 8)
        : (spl + (size_t)o * IN_F * 8 + (size_t)(c8 - IN_F / 8) * 8);
    const float4* s4 = reinterpret_cast<const float4*>(src);
    float4 lo = s4[0], hi = s4[1];
    uint4 pk;
    pk.x = f2bf(lo.x) | (f2bf(lo.y) << 16);
    pk.y = f2bf(lo.z) | (f2bf(lo.w) << 16);
    pk.z = f2bf(hi.x) | (f2bf(hi.y) << 16);
    pk.w = f2bf(hi.z) | (f2bf(hi.w) << 16);
    *reinterpret_cast<uint4*>(&B[(size_t)o * KTOT + (size_t)c8 * 8]) = pk;
}

// Fused A+B prep: blocks [0, NBA) build A (silu + basis), rest repack B.
__global__ __launch_bounds__(256)
void prep_fused(const float* __restrict__ x, const float* __restrict__ grid,
                const float* __restrict__ W, const float* __restrict__ spl,
                unsigned short* __restrict__ A, unsigned short* __restrict__ B)
{
    int b = blockIdx.x;
    if (b < NBA)
        prep_a_body(b * 256 + threadIdx.x, x, grid, A);
    else
        prep_b_body((b - NBA) * 256 + threadIdx.x, W, spl, B);
}

__global__ __launch_bounds__(256)
void prep_a_kernel(const float* __restrict__ x, const float* __restrict__ grid,
                   unsigned short* __restrict__ A)
{
    prep_a_body(blockIdx.x * blockDim.x + threadIdx.x, x, grid, A);
}

__global__ __launch_bounds__(256)
void prep_b_kernel(const float* __restrict__ W, const float* __restrict__ spl,
                   unsigned short* __restrict__ B)
{
    prep_b_body(blockIdx.x * blockDim.x + threadIdx.x, W, spl, B);
}

// ---------------------------------------------------------------------------
// R15 == R12 (proven best, 175.5 us): 256x256 tile, BK=64, 8 waves (2M x 4N,
// per-wave 128x64 = lowest LDS B/MAC reachable under the register wall),
// split-K=2. Barrier-minimal body: one s_barrier + one vmcnt(0) per K-tile,
// 64 MFMA between barriers, natural compiler scheduling. XOR-swizzled LDS
// (0 bank conflicts), BF16 partials, A-locality XCD remap (FETCH halved),
// fused prep, capped-grid reduce.
//   A row(mi) = wr*64 + (mi&3)*16 + (mi>>2)*128
//   B col(ni) = wc*32 + (ni&1)*16 + (ni>>1)*128
// ---------------------------------------------------------------------------
#define GLOAD(src, dst) __builtin_amdgcn_global_load_lds( \
    (const __attribute__((address_space(1))) void*)(src),  \
    (__attribute__((address_space(3))) void*)(dst), 16, 0, 0)
#define SBAR()  __builtin_amdgcn_s_barrier()
#define SCH0()  __builtin_amdgcn_sched_barrier(0)
#define VMC0()  asm volatile("s_waitcnt vmcnt(0)" ::: "memory")

__global__ __launch_bounds__(512, 2)
void gemm_kan2(const unsigned short* __restrict__ A,
               const unsigned short* __restrict__ B,
               unsigned short* __restrict__ P, int rows)
{
    __shared__ char lds[131072];   // A dbuf [0,64K), B dbuf [64K,128K)

    const int bid  = blockIdx.x;
    // A-locality remap: xcd = bid&7 (round-robin dispatch); bm == xcd (mod 8)
    // -> the 8 (bn,sk) siblings of one bm share one XCD's L2 A-slice.
    const int xcd  = bid & 7;
    const int j    = bid >> 3;
    const int sk   = j & 1;
    const int bn   = (j >> 1) & 3;
    const int bm   = (j >> 3) * 8 + xcd;
    const int tid  = threadIdx.x;
    const int wave = tid >> 6, lane = tid & 63;
    const int wr   = wave >> 2, wc = wave & 3;
    const int fr   = lane & 15, kg = lane >> 4;
    const int sw   = fr & 7;
    const int koff[2] = { (kg ^ sw) * 16, ((4 | kg) ^ sw) * 16 };
    const int k0 = sk * KHALF;

    // staging: thread covers row (tid>>3), 16B chunk (tid&7), inverse-swizzled k
    const int trow = tid >> 3;
    const int ksrc = ((tid & 7) ^ (trow & 7)) * 8;
    const unsigned short* gA = A + (size_t)(bm * 256 + trow) * KTOT + k0 + ksrc;
    const unsigned short* gB = B + (size_t)(bn * 256 + trow) * KTOT + k0 + ksrc;
    const size_t R64 = (size_t)64 * KTOT;

    f32x4 acc[8][4];
    const f32x4 zero = {0.f, 0.f, 0.f, 0.f};
    #pragma unroll
    for (int m = 0; m < 8; ++m)
        #pragma unroll
        for (int n = 0; n < 4; ++n) acc[m][n] = zero;

    // prologue: stage tile 0 -> buf0
    {
        char* dA = lds + tid * 16;
        char* dB = lds + 65536 + tid * 16;
        GLOAD(gA,           dA);           GLOAD(gA + R64,     dA + 8192);
        GLOAD(gA + 2 * R64, dA + 16384);   GLOAD(gA + 3 * R64, dA + 24576);
        GLOAD(gB,           dB);           GLOAD(gB + R64,     dB + 8192);
        GLOAD(gB + 2 * R64, dB + 16384);   GLOAD(gB + 3 * R64, dB + 24576);
        gA += 64; gB += 64;
    }
    VMC0(); SBAR(); SCH0();

    const int aOff = (wr * 64 + fr) * 128;   // + (mi&3)*2048; +16384 for hi half
    const int bOff = (wc * 32 + fr) * 128;   // + (ni&1)*2048; +16384 for hi half

    bf16x8 af[4][2], bfLo[2][2], bfHi[2][2];
    int u = 0;

    // MODE: 0 = steady (stages tile u+1), 1 = last tile (no staging)
    auto tile = [&](auto mC) {
        constexpr int MODE = decltype(mC)::value;
        char* bufA = lds + (u & 1) * 32768;
        char* bufB = lds + 65536 + (u & 1) * 32768;

        // ---- reads: af-lo, bfLo, bfHi (16 x ds_read_b128) ----
        #pragma unroll
        for (int mi = 0; mi < 4; ++mi)
            #pragma unroll
            for (int ks = 0; ks < 2; ++ks)
                af[mi][ks] = *(const bf16x8*)(bufA + aOff + mi * 2048 + koff[ks]);
        #pragma unroll
        for (int ni = 0; ni < 2; ++ni)
            #pragma unroll
            for (int ks = 0; ks < 2; ++ks) {
                bfLo[ni][ks] = *(const bf16x8*)(bufB + bOff + ni * 2048 + koff[ks]);
                bfHi[ni][ks] = *(const bf16x8*)(bufB + bOff + 16384 + ni * 2048 + koff[ks]);
            }

        // ---- stage tile u+1 into the other buffers ----
        if constexpr (MODE == 0) {
            char* dA = lds + ((u & 1) ^ 1) * 32768 + tid * 16;
            char* dB = lds + 65536 + ((u & 1) ^ 1) * 32768 + tid * 16;
            GLOAD(gA,           dA);           GLOAD(gA + R64,     dA + 8192);
            GLOAD(gA + 2 * R64, dA + 16384);   GLOAD(gA + 3 * R64, dA + 24576);
            GLOAD(gB,           dB);           GLOAD(gB + R64,     dB + 8192);
            GLOAD(gB + 2 * R64, dB + 16384);   GLOAD(gB + 3 * R64, dB + 24576);
            gA += 64; gB += 64;
        }
        SCH0();

        // ---- q00: af-lo x bfLo ----
        __builtin_amdgcn_s_setprio(1);
        #pragma unroll
        for (int mi = 0; mi < 4; ++mi)
            #pragma unroll
            for (int ni = 0; ni < 2; ++ni)
                #pragma unroll
                for (int ks = 0; ks < 2; ++ks)
                    acc[mi][ni] = __builtin_amdgcn_mfma_f32_16x16x32_bf16(
                        af[mi][ks], bfLo[ni][ks], acc[mi][ni], 0, 0, 0);
        __builtin_amdgcn_s_setprio(0);

        // ---- q01: af-lo x bfHi ----
        __builtin_amdgcn_s_setprio(1);
        #pragma unroll
        for (int mi = 0; mi < 4; ++mi)
            #pragma unroll
            for (int ni = 0; ni < 2; ++ni)
                #pragma unroll
                for (int ks = 0; ks < 2; ++ks)
                    acc[mi][2 + ni] = __builtin_amdgcn_mfma_f32_16x16x32_bf16(
                        af[mi][ks], bfHi[ni][ks], acc[mi][2 + ni], 0, 0, 0);
        __builtin_amdgcn_s_setprio(0);

        // ---- af-hi reads (8 x ds_read_b128), overlap q01 drain ----
        #pragma unroll
        for (int mi = 0; mi < 4; ++mi)
            #pragma unroll
            for (int ks = 0; ks < 2; ++ks)
                af[mi][ks] = *(const bf16x8*)(bufA + aOff + 16384 + mi * 2048 + koff[ks]);

        // ---- q10: af-hi x bfLo ----
        __builtin_amdgcn_s_setprio(1);
        #pragma unroll
        for (int mi = 0; mi < 4; ++mi)
            #pragma unroll
            for (int ni = 0; ni < 2; ++ni)
                #pragma unroll
                for (int ks = 0; ks < 2; ++ks)
                    acc[4 + mi][ni] = __builtin_amdgcn_mfma_f32_16x16x32_bf16(
                        af[mi][ks], bfLo[ni][ks], acc[4 + mi][ni], 0, 0, 0);
        __builtin_amdgcn_s_setprio(0);

        // ---- q11: af-hi x bfHi ----
        __builtin_amdgcn_s_setprio(1);
        #pragma unroll
        for (int mi = 0; mi < 4; ++mi)
            #pragma unroll
            for (int ni = 0; ni < 2; ++ni)
                #pragma unroll
                for (int ks = 0; ks < 2; ++ks)
                    acc[4 + mi][2 + ni] = __builtin_amdgcn_mfma_f32_16x16x32_bf16(
                        af[mi][ks], bfHi[ni][ks], acc[4 + mi][2 + ni], 0, 0, 0);
        __builtin_amdgcn_s_setprio(0);

        SCH0();
        if constexpr (MODE == 0) {
            VMC0();          // tile u+1 resident (issued a full tile ago)
            SBAR(); SCH0();  // all waves done reading buf(u); safe to overwrite next
        }
    };

    for (u = 0; u < NTILE - 1; ++u) tile(ModeT<0>{});
    tile(ModeT<1>{});

    // epilogue: write BF16 partials (interleaved-quadrant mapping)
    unsigned short* Pp = P + (size_t)sk * rows * OUT_F;
    const size_t orow0 = (size_t)bm * 256 + (size_t)wr * 64;
    const int    ocol0 = bn * 256 + wc * 32;
    #pragma unroll
    for (int n = 0; n < 4; ++n) {
        const int col = ocol0 + (n & 1) * 16 + (n >> 1) * 128 + fr;
        #pragma unroll
        for (int m = 0; m < 8; ++m) {
            const size_t r0 = orow0 + (m & 3) * 16 + (m >> 2) * 128 + kg * 4;
            #pragma unroll
            for (int j2 = 0; j2 < 4; ++j2)
                Pp[(r0 + j2) * OUT_F + col] = (unsigned short)f2bf(acc[m][n][j2]);
        }
    }
}

// out = P0 + P1 + bias   (bf16 partials, f32 out; 8 elems/thread)
__global__ __launch_bounds__(256)
void reduce_kan(const unsigned short* __restrict__ P,
                const float* __restrict__ bias,
                float* __restrict__ out, int n8, int skStride8)
{
    const ushortx8* p0 = (const ushortx8*)P;
    const ushortx8* p1 = p0 + skStride8;
    const float4* bv = (const float4*)bias;
    float4* o = (float4*)out;
    for (int i = blockIdx.x * blockDim.x + threadIdx.x; i < n8;
         i += gridDim.x * blockDim.x) {
        ushortx8 a = p0[i], b = p1[i];
        float4 c0 = bv[(i & 127) * 2], c1 = bv[(i & 127) * 2 + 1];
        float4 r0, r1;
        r0.x = bf2f(a[0]) + bf2f(b[0]) + c0.x;
        r0.y = bf2f(a[1]) + bf2f(b[1]) + c0.y;
        r0.z = bf2f(a[2]) + bf2f(b[2]) + c0.z;
        r0.w = bf2f(a[3]) + bf2f(b[3]) + c0.w;
        r1.x = bf2f(a[4]) + bf2f(b[4]) + c1.x;
        r1.y = bf2f(a[5]) + bf2f(b[5]) + c1.y;
        r1.z = bf2f(a[6]) + bf2f(b[6]) + c1.z;
        r1.w = bf2f(a[7]) + bf2f(b[7]) + c1.w;
        o[i * 2]     = r0;
        o[i * 2 + 1] = r1;
    }
}

extern "C" void kernel_launch(void* const* d_in, const int* in_sizes, int n_in,
                              void* d_out, int out_size, void* d_ws, size_t ws_size,
                              hipStream_t stream)
{
    const float* x    = (const float*)d_in[0];
    const float* W    = (const float*)d_in[1];
    const float* bias = (const float*)d_in[2];
    const float* spl  = (const float*)d_in[3];
    const float* grid = (const float*)d_in[4];
    float* out = (float*)d_out;

    unsigned short* Bw = (unsigned short*)d_ws;               // 18.9 MB
    unsigned short* Aw = Bw + (size_t)OUT_F * KTOT;

    // per-row ws: A bf16 (18432 B) + 2x bf16 partial (4096 B) = 22528 B
    const size_t bBytes = (size_t)OUT_F * KTOT * 2;
    size_t avail = ws_size > bBytes ? ws_size - bBytes : 0;
    long maxRows = (long)(avail / 22528);
    int chunk = (maxRows >= TOKENS) ? TOKENS : (int)((maxRows / 256) * 256);
    if (chunk < 256) chunk = 256;
    unsigned short* Pp = Aw + (size_t)chunk * KTOT;

    if (chunk == TOKENS) {
        // fused prep (A + B in one BW-bound sweep), then one GEMM + reduce
        prep_fused<<<NBA + NBB, 256, 0, stream>>>(x, grid, W, spl, Aw, Bw);
        gemm_kan2<<<(TOKENS >> 8) * 8, 512, 0, stream>>>(Aw, Bw, Pp, TOKENS);
        int n8 = TOKENS * 128;
        reduce_kan<<<2048, 256, 0, stream>>>(Pp, bias, out, n8, n8);
    } else {
        prep_b_kernel<<<NBB, 256, 0, stream>>>(W, spl, Bw);
        for (int t0 = 0; t0 < TOKENS; t0 += chunk) {
            int rows = (TOKENS - t0 < chunk) ? (TOKENS - t0) : chunk;
            prep_a_kernel<<<(rows * IN_F) / 256, 256, 0, stream>>>(
                x + (size_t)t0 * IN_F, grid, Aw);
            gemm_kan2<<<(rows >> 8) * 8, 512, 0, stream>>>(Aw, Bw, Pp, rows);
            int n8 = rows * 128;
            int rblocks = (n8 + 255) / 256; if (rblocks > 2048) rblocks = 2048;
            reduce_kan<<<rblocks, 256, 0, stream>>>(
                Pp, bias, out + (size_t)t0 * OUT_F, n8, n8);
        }
    }
}